// Round 14
// baseline (426.363 us; speedup 1.0000x reference)
//
#include <hip/hip_runtime.h>
#include <hip/hip_bf16.h>

typedef unsigned short u16;
typedef unsigned int u32;

#define MAXB 2048

__device__ __forceinline__ float bf2f(u16 u) { return __uint_as_float(((u32)u) << 16); }
__device__ __forceinline__ float bl(u32 u) { return __uint_as_float(u << 16); }
__device__ __forceinline__ float bh(u32 u) { return __uint_as_float(u & 0xffff0000u); }
__device__ __forceinline__ u16 f2bf(float f) {
    u32 u = __float_as_uint(f);
    u += 0x7fffu + ((u >> 16) & 1u);   // round-to-nearest-even
    return (u16)(u >> 16);
}
__device__ __forceinline__ float lrelu(float x) { return x > 0.f ? x : 0.2f * x; }
__device__ __forceinline__ int clampi(int v, int lo, int hi) {
    return v < lo ? lo : (v > hi ? hi : v);
}
__device__ __forceinline__ float load1(const void* base, int idx, int f32) {
    return f32 ? ((const float*)base)[idx] : bf2f(((const u16*)base)[idx]);
}
// softmax without max-shift: clamp keeps exp finite; shift-invariance => same ratios
__device__ __forceinline__ float cexpf(float a) { return expf(fminf(a, 30.f)); }

// ---------------- dtype detector ---------------------------------------------------------
__global__ void k_detect(const u32* __restrict__ xw, int* __restrict__ flag) {
    int lane = threadIdx.x & 63;
    int cnt = 0;
    #pragma unroll
    for (int j = 0; j < 4; j++) {
        u32 w = xw[lane * 4 + j];
        int e0 = (int)((w >> 7) & 0xffu);
        int e1 = (int)((w >> 23) & 0xffu);
        cnt += (e0 >= 0x60 && e0 <= 0x8f);
        cnt += (e1 >= 0x60 && e1 <= 0x8f);
    }
    #pragma unroll
    for (int off = 32; off > 0; off >>= 1) cnt += __shfl_xor(cnt, off);
    if (lane == 0) *flag = (cnt < 480) ? 1 : 0;
}

// ---------------- constants + fp32 expansion of attention vectors -----------------------
__global__ void k_consts(const void* We1, const void* ae1, const void* We2, const void* ae2,
                         const void* as1, const void* ad1, const void* as2, const void* ad2,
                         const int* __restrict__ flag, float* __restrict__ consts) {
    int f = *flag;
    int t = threadIdx.x;
    if (t < 4) {
        float s = 0.f;
        for (int c = 0; c < 32; c++) s += load1(We1, t * 32 + c, f) * load1(ae1, t * 32 + c, f);
        consts[t] = s;
    } else if (t == 4) {
        float s = 0.f;
        for (int c = 0; c < 64; c++) s += load1(We2, c, f) * load1(ae2, c, f);
        consts[4] = s;
    }
    if (t < 128) {
        consts[8 + t] = load1(as1, t, f);
        consts[136 + t] = load1(ad1, t, f);
    }
    if (t < 64) {
        consts[264 + t] = load1(as2, t, f);
        consts[328 + t] = load1(ad2, t, f);
    }
}

// ---------------- gemmA: h1[N,128] = X[N,128] @ W1, PAIRED u32 output -------------------
// Ws2[k][c] = (W[k][c], W[k][c+64]) fp32 pairs; k-step 8. LDS 80KB -> 2 blocks/CU.
__global__ __launch_bounds__(256, 2) void k_gemmA(
    const void* __restrict__ X, const void* __restrict__ Wg,
    const int* __restrict__ flag, u32* __restrict__ Y, int nrows) {
    constexpr int K = 128;
    constexpr int ROWS = 32;
    __shared__ float2 Ws2[K * 64];
    __shared__ float Xs[ROWS * K];

    const int f = *flag;
    const bool fX = (f != 0), fW = (f != 0);
    const int tid = threadIdx.x, wid = tid >> 6, lane = tid & 63;

    for (int idx = tid; idx < K * 64; idx += 256) {
        int k = idx >> 6, c = idx & 63;
        float a, b;
        if (fW) {
            a = ((const float*)Wg)[k * 128 + c];
            b = ((const float*)Wg)[k * 128 + c + 64];
        } else {
            a = bf2f(((const u16*)Wg)[k * 128 + c]);
            b = bf2f(((const u16*)Wg)[k * 128 + c + 64]);
        }
        Ws2[idx] = make_float2(a, b);
    }

    const int sr = tid >> 3;
    const int sc = (tid & 7) * 16;

    for (int base = blockIdx.x * ROWS; base < nrows; base += gridDim.x * ROWS) {
        __syncthreads();
        {
            int row = base + sr;
            float* xs = &Xs[sr * K + sc];
            if (row < nrows) {
                if (fX) {
                    const float* xp = (const float*)X + (size_t)row * K + sc;
                    float4 a = *(const float4*)xp;
                    float4 b = *(const float4*)(xp + 4);
                    float4 c = *(const float4*)(xp + 8);
                    float4 d = *(const float4*)(xp + 12);
                    xs[0] = a.x; xs[1] = a.y; xs[2] = a.z; xs[3] = a.w;
                    xs[4] = b.x; xs[5] = b.y; xs[6] = b.z; xs[7] = b.w;
                    xs[8] = c.x; xs[9] = c.y; xs[10] = c.z; xs[11] = c.w;
                    xs[12] = d.x; xs[13] = d.y; xs[14] = d.z; xs[15] = d.w;
                } else {
                    const u16* xp = (const u16*)X + (size_t)row * K + sc;
                    uint4 a = *(const uint4*)xp;
                    uint4 b = *(const uint4*)(xp + 8);
                    xs[0] = bl(a.x); xs[1] = bh(a.x); xs[2] = bl(a.y); xs[3] = bh(a.y);
                    xs[4] = bl(a.z); xs[5] = bh(a.z); xs[6] = bl(a.w); xs[7] = bh(a.w);
                    xs[8] = bl(b.x); xs[9] = bh(b.x); xs[10] = bl(b.y); xs[11] = bh(b.y);
                    xs[12] = bl(b.z); xs[13] = bh(b.z); xs[14] = bl(b.w); xs[15] = bh(b.w);
                }
            } else {
                #pragma unroll
                for (int j = 0; j < 16; j++) xs[j] = 0.f;
            }
        }
        __syncthreads();

        float acc0[8] = {0.f, 0.f, 0.f, 0.f, 0.f, 0.f, 0.f, 0.f};
        float acc1[8] = {0.f, 0.f, 0.f, 0.f, 0.f, 0.f, 0.f, 0.f};
        #pragma unroll 2
        for (int k = 0; k < K; k += 8) {
            float2 w0 = Ws2[(k + 0) * 64 + lane];
            float2 w1 = Ws2[(k + 1) * 64 + lane];
            float2 w2 = Ws2[(k + 2) * 64 + lane];
            float2 w3 = Ws2[(k + 3) * 64 + lane];
            float2 w4 = Ws2[(k + 4) * 64 + lane];
            float2 w5 = Ws2[(k + 5) * 64 + lane];
            float2 w6 = Ws2[(k + 6) * 64 + lane];
            float2 w7 = Ws2[(k + 7) * 64 + lane];
            #pragma unroll
            for (int rr = 0; rr < 8; rr++) {
                float4 xa = *(const float4*)&Xs[(wid * 8 + rr) * K + k];
                float4 xb = *(const float4*)&Xs[(wid * 8 + rr) * K + k + 4];
                acc0[rr] += xa.x * w0.x + xa.y * w1.x + xa.z * w2.x + xa.w * w3.x
                          + xb.x * w4.x + xb.y * w5.x + xb.z * w6.x + xb.w * w7.x;
                acc1[rr] += xa.x * w0.y + xa.y * w1.y + xa.z * w2.y + xa.w * w3.y
                          + xb.x * w4.y + xb.y * w5.y + xb.z * w6.y + xb.w * w7.y;
            }
        }

        #pragma unroll
        for (int rr = 0; rr < 8; rr++) {
            int row = base + wid * 8 + rr;
            if (row < nrows) {
                u32 w = (u32)f2bf(acc0[rr]) | ((u32)f2bf(acc1[rr]) << 16);
                Y[(size_t)row * 64 + lane] = w;
            }
        }
    }
}

// ---------------- gemmB: h2[N,64] = agg1(paired u32) @ W2, + FUSED coef2 ----------------
// Xs32 raw paired words (8KB); Ws2[w][c] = (W2[w][c], W2[w+64][c]) (32KB) -> 4 blocks/CU.
__global__ __launch_bounds__(256, 4) void k_gemmB(
    const u32* __restrict__ Xp, const void* __restrict__ Wg,
    const int* __restrict__ flag, const float* __restrict__ consts,
    u16* __restrict__ Y, float* __restrict__ asrc2, float* __restrict__ adst2, int nrows) {
    constexpr int ROWS = 32;
    __shared__ float2 Ws2[64 * 64];
    __shared__ u32 Xs32[ROWS * 64];

    const int f = *flag;
    const bool fW = (f != 0);
    const int tid = threadIdx.x, wid = tid >> 6, lane = tid & 63;
    const float as2l = consts[264 + lane];
    const float ad2l = consts[328 + lane];

    for (int idx = tid; idx < 64 * 64; idx += 256) {
        int w = idx >> 6, c = idx & 63;
        float a, b;
        if (fW) {
            a = ((const float*)Wg)[w * 64 + c];
            b = ((const float*)Wg)[(w + 64) * 64 + c];
        } else {
            a = bf2f(((const u16*)Wg)[w * 64 + c]);
            b = bf2f(((const u16*)Wg)[(w + 64) * 64 + c]);
        }
        Ws2[idx] = make_float2(a, b);
    }

    const int sr = tid >> 3;          // staging row 0..31
    const int sc = (tid & 7) * 8;     // staging word 0..56

    for (int base = blockIdx.x * ROWS; base < nrows; base += gridDim.x * ROWS) {
        __syncthreads();
        {
            int row = base + sr;
            u32* xs = &Xs32[sr * 64 + sc];
            if (row < nrows) {
                uint4 a = *(const uint4*)&Xp[(size_t)row * 64 + sc];
                uint4 b = *(const uint4*)&Xp[(size_t)row * 64 + sc + 4];
                xs[0] = a.x; xs[1] = a.y; xs[2] = a.z; xs[3] = a.w;
                xs[4] = b.x; xs[5] = b.y; xs[6] = b.z; xs[7] = b.w;
            } else {
                #pragma unroll
                for (int j = 0; j < 8; j++) xs[j] = 0u;
            }
        }
        __syncthreads();

        float acc[8] = {0.f, 0.f, 0.f, 0.f, 0.f, 0.f, 0.f, 0.f};
        #pragma unroll 2
        for (int w = 0; w < 64; w += 4) {
            float2 p0 = Ws2[(w + 0) * 64 + lane];
            float2 p1 = Ws2[(w + 1) * 64 + lane];
            float2 p2 = Ws2[(w + 2) * 64 + lane];
            float2 p3 = Ws2[(w + 3) * 64 + lane];
            #pragma unroll
            for (int rr = 0; rr < 8; rr++) {
                uint4 xw = *(const uint4*)&Xs32[(wid * 8 + rr) * 64 + w];
                acc[rr] += bl(xw.x) * p0.x + bh(xw.x) * p0.y
                         + bl(xw.y) * p1.x + bh(xw.y) * p1.y
                         + bl(xw.z) * p2.x + bh(xw.z) * p2.y
                         + bl(xw.w) * p3.x + bh(xw.w) * p3.y;
            }
        }

        #pragma unroll
        for (int rr = 0; rr < 8; rr++) {
            int row = base + wid * 8 + rr;
            if (row < nrows) {
                u16 hb16 = f2bf(acc[rr]);
                Y[(size_t)row * 64 + lane] = hb16;
                // fused coef2 on the bf16-rounded value (matches previous pipeline)
                float hv = bf2f(hb16);
                float t1 = hv * as2l;
                float t2 = hv * ad2l;
                #pragma unroll
                for (int off = 32; off > 0; off >>= 1) {
                    t1 += __shfl_xor(t1, off);
                    t2 += __shfl_xor(t2, off);
                }
                if (lane == 0) {
                    asrc2[row] = t1;
                    adst2[row] = t2;
                }
            }
        }
    }
}

// ---------------- coef1: paired h1 -> asrc1/adst1 [N][4] --------------------------------
__global__ void k_coef1(const u32* __restrict__ hp, const float* __restrict__ consts,
                        float* __restrict__ asrc, float* __restrict__ adst, int n) {
    int i = blockIdx.x * 256 + threadIdx.x;
    if (i >= n * 2) return;
    int node = i >> 1, g = i & 1;
    const u32* w = hp + (size_t)node * 64 + g * 32;
    const float* asA = consts + 8 + g * 32;
    const float* adA = consts + 136 + g * 32;
    const float* asB = consts + 8 + (g + 2) * 32;
    const float* adB = consts + 136 + (g + 2) * 32;
    float sA1 = 0.f, sA2 = 0.f, sB1 = 0.f, sB2 = 0.f;
    #pragma unroll
    for (int c = 0; c < 32; c += 4) {
        uint4 q = *(const uint4*)&w[c];
        float l0 = bl(q.x), h0 = bh(q.x), l1 = bl(q.y), h1 = bh(q.y);
        float l2 = bl(q.z), h2 = bh(q.z), l3 = bl(q.w), h3 = bh(q.w);
        sA1 += l0 * asA[c] + l1 * asA[c + 1] + l2 * asA[c + 2] + l3 * asA[c + 3];
        sA2 += l0 * adA[c] + l1 * adA[c + 1] + l2 * adA[c + 2] + l3 * adA[c + 3];
        sB1 += h0 * asB[c] + h1 * asB[c + 1] + h2 * asB[c + 2] + h3 * asB[c + 3];
        sB2 += h0 * adB[c] + h1 * adB[c + 1] + h2 * adB[c + 2] + h3 * adB[c + 3];
    }
    asrc[node * 4 + g] = sA1;     adst[node * 4 + g] = sA2;
    asrc[node * 4 + g + 2] = sB1; adst[node * 4 + g + 2] = sB2;
}

// ---------------- CSR build -------------------------------------------------------------
__global__ __launch_bounds__(256) void k_bhist(const int* __restrict__ dst,
                                               int* __restrict__ cnt, int* __restrict__ bcnt,
                                               int E, int n, int B) {
    __shared__ int lh[MAXB];
    for (int i = threadIdx.x; i < B; i += 256) lh[i] = 0;
    __syncthreads();
    int stride = gridDim.x * 256;
    for (int e = blockIdx.x * 256 + threadIdx.x; e < E; e += stride) {
        int d = clampi(dst[e], 0, n - 1);
        atomicAdd(&cnt[d], 1);
        atomicAdd(&lh[d >> 8], 1);
    }
    __syncthreads();
    for (int i = threadIdx.x; i < B; i += 256)
        if (lh[i]) atomicAdd(&bcnt[i], lh[i]);
}
__global__ void k_scan1(const int* __restrict__ cnt, int* __restrict__ part,
                        int* __restrict__ bsum, int n) {
    __shared__ int buf[256];
    int i = blockIdx.x * 256 + threadIdx.x;
    int v = (i < n) ? cnt[i] : 0;
    buf[threadIdx.x] = v;
    __syncthreads();
    for (int off = 1; off < 256; off <<= 1) {
        int t = (threadIdx.x >= off) ? buf[threadIdx.x - off] : 0;
        __syncthreads();
        buf[threadIdx.x] += t;
        __syncthreads();
    }
    if (i < n) part[i] = buf[threadIdx.x];
    if (threadIdx.x == 255) bsum[blockIdx.x] = buf[255];
}
__global__ void k_scan2(int* __restrict__ bsum, int nb) {
    __shared__ int buf[256];
    int t = threadIdx.x;
    int v = (t < nb) ? bsum[t] : 0;
    buf[t] = v;
    __syncthreads();
    for (int off = 1; off < 256; off <<= 1) {
        int tt = (t >= off) ? buf[t - off] : 0;
        __syncthreads();
        buf[t] += tt;
        __syncthreads();
    }
    if (t < nb) bsum[t] = buf[t] - v;   // exclusive
}
__global__ void k_scan3(int* __restrict__ roff, const int* __restrict__ bsum,
                        int* __restrict__ rpos, int n) {
    int i = blockIdx.x * 256 + threadIdx.x;
    if (i > n) return;
    int v;
    if (i == 0) { v = 0; roff[0] = 0; }
    else { v = roff[i] + bsum[(i - 1) >> 8]; roff[i] = v; }
    if (i < n) rpos[i] = v;
}
__global__ void k_bscan(const int* __restrict__ bcnt, int* __restrict__ bbase,
                        int* __restrict__ bfront, int B) {
    if (threadIdx.x == 0) {
        int acc = 0;
        for (int i = 0; i < B; i++) { bbase[i] = acc; bfront[i] = acc; acc += bcnt[i]; }
        bbase[B] = acc;
    }
}
// binA: tile-ranked bucket scatter -> staged int4 {src, dst, ea_bits, 0}
__global__ __launch_bounds__(256) void k_binA(
    const int* __restrict__ dst, const int* __restrict__ src, const void* eattr,
    const int* __restrict__ flag, int* __restrict__ bfront, int4* __restrict__ staged,
    int E, int n, int B) {
    __shared__ int lhist[MAXB];
    __shared__ int lbase[MAXB];
    int f = *flag;
    constexpr int T = 2048;
    for (int tile = blockIdx.x; (long long)tile * T < E; tile += gridDim.x) {
        int base = tile * T;
        for (int i = threadIdx.x; i < B; i += 256) lhist[i] = 0;
        __syncthreads();
        int sj0, sj1, sj2, sj3, sj4, sj5, sj6, sj7;
        int dj0, dj1, dj2, dj3, dj4, dj5, dj6, dj7;
        int rj0, rj1, rj2, rj3, rj4, rj5, rj6, rj7;
        int ej0, ej1, ej2, ej3, ej4, ej5, ej6, ej7;
        #define BINA_LOAD(J, SJ, DJ, RJ, EJ)                                   \
        {                                                                      \
            int idx = base + (J) * 256 + threadIdx.x;                          \
            bool v = idx < E;                                                  \
            int d = v ? clampi(dst[idx], 0, n - 1) : 0;                        \
            SJ = v ? clampi(src[idx], 0, n - 1) : 0;                           \
            EJ = v ? __float_as_int(load1(eattr, idx, f)) : 0;                 \
            DJ = d;                                                            \
            RJ = v ? atomicAdd(&lhist[d >> 8], 1) : -1;                        \
        }
        BINA_LOAD(0, sj0, dj0, rj0, ej0)
        BINA_LOAD(1, sj1, dj1, rj1, ej1)
        BINA_LOAD(2, sj2, dj2, rj2, ej2)
        BINA_LOAD(3, sj3, dj3, rj3, ej3)
        BINA_LOAD(4, sj4, dj4, rj4, ej4)
        BINA_LOAD(5, sj5, dj5, rj5, ej5)
        BINA_LOAD(6, sj6, dj6, rj6, ej6)
        BINA_LOAD(7, sj7, dj7, rj7, ej7)
        #undef BINA_LOAD
        __syncthreads();
        for (int i = threadIdx.x; i < B; i += 256) {
            int c = lhist[i];
            lbase[i] = c ? atomicAdd(&bfront[i], c) : 0;
        }
        __syncthreads();
        #define BINA_STORE(SJ, DJ, RJ, EJ)                                     \
        if (RJ >= 0) {                                                         \
            long long q = (long long)lbase[DJ >> 8] + RJ;                      \
            if (q >= 0 && q < E) {                                             \
                int4 v; v.x = SJ; v.y = DJ; v.z = EJ; v.w = 0;                 \
                staged[q] = v;                                                 \
            }                                                                  \
        }
        BINA_STORE(sj0, dj0, rj0, ej0)
        BINA_STORE(sj1, dj1, rj1, ej1)
        BINA_STORE(sj2, dj2, rj2, ej2)
        BINA_STORE(sj3, dj3, rj3, ej3)
        BINA_STORE(sj4, dj4, rj4, ej4)
        BINA_STORE(sj5, dj5, rj5, ej5)
        BINA_STORE(sj6, dj6, rj6, ej6)
        BINA_STORE(sj7, dj7, rj7, ej7)
        #undef BINA_STORE
        __syncthreads();
    }
}
// binB: one workgroup per bucket; writes confined to the bucket's edata window
__global__ __launch_bounds__(256) void k_binB(
    const int4* __restrict__ staged, const int* __restrict__ bbase,
    const int* __restrict__ roff, int2* __restrict__ edata, int N, int E, int B) {
    __shared__ int lpos[256];
    int k = blockIdx.x;
    int dlo = k << 8;
    int t = threadIdx.x;
    int dn = dlo + t;
    lpos[t] = (dn < N) ? roff[dn] : 0;
    __syncthreads();
    int lo = clampi(bbase[k], 0, E);
    int hi = clampi(bbase[k + 1], lo, E);
    for (int i = lo + t; i < hi; i += 256) {
        int4 v = staged[i];
        int p = atomicAdd(&lpos[v.y & 255], 1);
        if (p >= 0 && p < E) edata[p] = make_int2(v.x, v.z);
    }
}
// fallback single-pass scatter
__global__ void k_scatter(const int* __restrict__ dst, const int* __restrict__ src,
                          const void* eattr, const int* __restrict__ flag,
                          int* __restrict__ rpos, int2* __restrict__ edata, int E, int n) {
    int f = *flag;
    int e = blockIdx.x * 256 + threadIdx.x;
    if (e < E) {
        int d = clampi(dst[e], 0, n - 1);
        int s = clampi(src[e], 0, n - 1);
        float ea = load1(eattr, e, f);
        int p = atomicAdd(&rpos[d], 1);
        if (p >= 0 && p < E) {
            int2 v; v.x = s; v.y = __float_as_int(ea);
            edata[p] = v;
        }
    }
}

// ---------------- gat1, CACHED: fused fast path, no-max softmax, LDS weights, 4x MLP ----
__global__ __launch_bounds__(256) void k_gat1c(
    const u32* __restrict__ hp, const float* __restrict__ asrc, const float* __restrict__ adst,
    const int2* __restrict__ edata, const int* __restrict__ roff,
    const int* __restrict__ flag, const float* __restrict__ consts, const void* bias,
    float* __restrict__ al, u32* __restrict__ out, int n, int E) {
    __shared__ float4 wls[4][64];
    int f = *flag;
    int gtid = blockIdx.x * 256 + threadIdx.x;
    int wv = gtid >> 6, lane = gtid & 63;
    int wid = (threadIdx.x >> 6);
    int nw = (gridDim.x * 256) >> 6;
    const float c0 = consts[0], c1 = consts[1], c2 = consts[2], c3 = consts[3];
    const int hsel = lane >> 5;
    const float biasA = load1(bias, lane, f);
    const float biasB = load1(bias, 64 + lane, f);

    for (int d = wv; d < n; d += nw) {
        int s0 = clampi(roff[d], 0, E);
        int s1 = clampi(roff[d + 1], s0, E);
        int deg = s1 - s0;
        float4 adv = *(const float4*)&adst[d * 4];
        float accA = 0.f, accB = 0.f;

        if (deg <= 64) {
            bool v = lane < deg;
            int s = 0;
            float e0 = 0.f, e1 = 0.f, e2 = 0.f, e3 = 0.f;
            if (v) {
                int2 ed = edata[s0 + lane];
                s = ed.x;
                float ea = __int_as_float(ed.y);
                float4 av = *(const float4*)&asrc[(size_t)s * 4];
                e0 = cexpf(lrelu(av.x + adv.x + ea * c0));
                e1 = cexpf(lrelu(av.y + adv.y + ea * c1));
                e2 = cexpf(lrelu(av.z + adv.z + ea * c2));
                e3 = cexpf(lrelu(av.w + adv.w + ea * c3));
            }
            float d0 = e0, d1 = e1, d2 = e2, d3 = e3;
            #pragma unroll
            for (int off = 32; off > 0; off >>= 1) {
                d0 += __shfl_xor(d0, off); d1 += __shfl_xor(d1, off);
                d2 += __shfl_xor(d2, off); d3 += __shfl_xor(d3, off);
            }
            float i0 = 1.f / (d0 + 1e-16f), i1 = 1.f / (d1 + 1e-16f);
            float i2 = 1.f / (d2 + 1e-16f), i3 = 1.f / (d3 + 1e-16f);
            if (v) wls[wid][lane] = make_float4(e0 * i0, e1 * i1, e2 * i2, e3 * i3);

            int j = 0;
            for (; j + 4 <= deg; j += 4) {
                int sa = __shfl(s, j), sb = __shfl(s, j + 1);
                int sc_ = __shfl(s, j + 2), sd = __shfl(s, j + 3);
                u32 ha = hp[(size_t)sa * 64 + lane];
                u32 hb = hp[(size_t)sb * 64 + lane];
                u32 hc = hp[(size_t)sc_ * 64 + lane];
                u32 hd = hp[(size_t)sd * 64 + lane];
                float4 wa = wls[wid][j], wb = wls[wid][j + 1];
                float4 wc = wls[wid][j + 2], wd = wls[wid][j + 3];
                accA += (hsel ? wa.y : wa.x) * bl(ha); accB += (hsel ? wa.w : wa.z) * bh(ha);
                accA += (hsel ? wb.y : wb.x) * bl(hb); accB += (hsel ? wb.w : wb.z) * bh(hb);
                accA += (hsel ? wc.y : wc.x) * bl(hc); accB += (hsel ? wc.w : wc.z) * bh(hc);
                accA += (hsel ? wd.y : wd.x) * bl(hd); accB += (hsel ? wd.w : wd.z) * bh(hd);
            }
            for (; j < deg; j++) {
                int sj = __shfl(s, j);
                u32 hw = hp[(size_t)sj * 64 + lane];
                float4 w = wls[wid][j];
                accA += (hsel ? w.y : w.x) * bl(hw);
                accB += (hsel ? w.w : w.z) * bh(hw);
            }
        } else {
            // general path (rare): 2 passes (exp+sum, then weighted gather)
            float d0 = 0.f, d1 = 0.f, d2 = 0.f, d3 = 0.f;
            for (int idx = s0 + lane; idx < s1; idx += 64) {
                int2 ed = edata[idx];
                int s = ed.x;
                float ea = __int_as_float(ed.y);
                float4 av = *(const float4*)&asrc[(size_t)s * 4];
                float e0 = cexpf(lrelu(av.x + adv.x + ea * c0));
                float e1 = cexpf(lrelu(av.y + adv.y + ea * c1));
                float e2 = cexpf(lrelu(av.z + adv.z + ea * c2));
                float e3 = cexpf(lrelu(av.w + adv.w + ea * c3));
                *(float4*)&al[(size_t)idx * 4] = make_float4(e0, e1, e2, e3);
                d0 += e0; d1 += e1; d2 += e2; d3 += e3;
            }
            #pragma unroll
            for (int off = 32; off > 0; off >>= 1) {
                d0 += __shfl_xor(d0, off); d1 += __shfl_xor(d1, off);
                d2 += __shfl_xor(d2, off); d3 += __shfl_xor(d3, off);
            }
            float i0 = 1.f / (d0 + 1e-16f), i1 = 1.f / (d1 + 1e-16f);
            float i2 = 1.f / (d2 + 1e-16f), i3 = 1.f / (d3 + 1e-16f);
            float iA = hsel ? i1 : i0, iB = hsel ? i3 : i2;
            for (int idx = s0; idx < s1; idx++) {
                int s = edata[idx].x;
                float4 ex = *(const float4*)&al[(size_t)idx * 4];
                float wA = (hsel ? ex.y : ex.x) * iA;
                float wB = (hsel ? ex.w : ex.z) * iB;
                u32 hw = hp[(size_t)s * 64 + lane];
                accA += wA * bl(hw);
                accB += wB * bh(hw);
            }
        }
        float rA = fmaxf(accA + biasA, 0.f);   // fused ReLU
        float rB = fmaxf(accB + biasB, 0.f);
        out[(size_t)d * 64 + lane] = (u32)f2bf(rA) | ((u32)f2bf(rB) << 16);
    }
}

// ---------------- gat2, CACHED: fused fast path, no-max softmax -------------------------
__global__ __launch_bounds__(256) void k_gat2c(
    const u16* __restrict__ h, const float* __restrict__ asrc, const float* __restrict__ adst,
    const int2* __restrict__ edata, const int* __restrict__ roff,
    const int* __restrict__ flag, const float* __restrict__ consts, const void* bias,
    float* __restrict__ al, u16* __restrict__ out, int n, int E) {
    __shared__ float wls[4][64];
    int f = *flag;
    int gtid = blockIdx.x * 256 + threadIdx.x;
    int wv = gtid >> 6, lane = gtid & 63;
    int wid = (threadIdx.x >> 6);
    int nw = (gridDim.x * 256) >> 6;
    const float C = consts[4];
    const float biasL = load1(bias, lane, f);

    for (int d = wv; d < n; d += nw) {
        int s0 = clampi(roff[d], 0, E);
        int s1 = clampi(roff[d + 1], s0, E);
        int deg = s1 - s0;
        float ad = adst[d];
        float acc = 0.f;

        if (deg <= 64) {
            bool v = lane < deg;
            int s = 0;
            float e = 0.f;
            if (v) {
                int2 ed = edata[s0 + lane];
                s = ed.x;
                e = cexpf(lrelu(asrc[s] + ad + __int_as_float(ed.y) * C));
            }
            float den = e;
            #pragma unroll
            for (int off = 32; off > 0; off >>= 1) den += __shfl_xor(den, off);
            float inv = 1.f / (den + 1e-16f);
            if (v) wls[wid][lane] = e * inv;

            int j = 0;
            for (; j + 4 <= deg; j += 4) {
                int sa = __shfl(s, j), sb = __shfl(s, j + 1);
                int sc_ = __shfl(s, j + 2), sd = __shfl(s, j + 3);
                float ha = bf2f(h[(size_t)sa * 64 + lane]);
                float hb = bf2f(h[(size_t)sb * 64 + lane]);
                float hc = bf2f(h[(size_t)sc_ * 64 + lane]);
                float hd = bf2f(h[(size_t)sd * 64 + lane]);
                acc += wls[wid][j] * ha + wls[wid][j + 1] * hb
                     + wls[wid][j + 2] * hc + wls[wid][j + 3] * hd;
            }
            for (; j < deg; j++) {
                int sj = __shfl(s, j);
                acc += wls[wid][j] * bf2f(h[(size_t)sj * 64 + lane]);
            }
        } else {
            float den = 0.f;
            for (int idx = s0 + lane; idx < s1; idx += 64) {
                int2 ed = edata[idx];
                float e = cexpf(lrelu(asrc[ed.x] + ad + __int_as_float(ed.y) * C));
                al[idx] = e;
                den += e;
            }
            #pragma unroll
            for (int off = 32; off > 0; off >>= 1) den += __shfl_xor(den, off);
            float inv = 1.f / (den + 1e-16f);
            for (int idx = s0; idx < s1; idx++) {
                int s = edata[idx].x;
                acc += al[idx] * inv * bf2f(h[(size_t)s * 64 + lane]);
            }
        }
        out[(size_t)d * 64 + lane] = f2bf(acc + biasL);
    }
}

// ---------------- gat1/gat2 FALLBACK (recompute, no al cache) ---------------------------
__global__ __launch_bounds__(256) void k_gat1f(
    const u32* __restrict__ hp, const float* __restrict__ asrc, const float* __restrict__ adst,
    const int2* __restrict__ edata, const int* __restrict__ roff,
    const int* __restrict__ flag, const float* __restrict__ consts, const void* bias,
    u32* __restrict__ out, int n, int E) {
    int f = *flag;
    int gtid = blockIdx.x * 256 + threadIdx.x;
    int wv = gtid >> 6, lane = gtid & 63;
    int nw = (gridDim.x * 256) >> 6;
    const float c0 = consts[0], c1 = consts[1], c2 = consts[2], c3 = consts[3];
    const int hsel = lane >> 5;
    const float biasA = load1(bias, lane, f);
    const float biasB = load1(bias, 64 + lane, f);

    for (int d = wv; d < n; d += nw) {
        int s0 = clampi(roff[d], 0, E);
        int s1 = clampi(roff[d + 1], s0, E);
        float4 adv = *(const float4*)&adst[d * 4];
        float d0 = 0.f, d1 = 0.f, d2 = 0.f, d3 = 0.f;
        for (int idx = s0 + lane; idx < s1; idx += 64) {
            int2 ed = edata[idx];
            float ea = __int_as_float(ed.y);
            float4 av = *(const float4*)&asrc[(size_t)ed.x * 4];
            d0 += cexpf(lrelu(av.x + adv.x + ea * c0));
            d1 += cexpf(lrelu(av.y + adv.y + ea * c1));
            d2 += cexpf(lrelu(av.z + adv.z + ea * c2));
            d3 += cexpf(lrelu(av.w + adv.w + ea * c3));
        }
        #pragma unroll
        for (int off = 32; off > 0; off >>= 1) {
            d0 += __shfl_xor(d0, off); d1 += __shfl_xor(d1, off);
            d2 += __shfl_xor(d2, off); d3 += __shfl_xor(d3, off);
        }
        float i0 = 1.f / (d0 + 1e-16f), i1 = 1.f / (d1 + 1e-16f);
        float i2 = 1.f / (d2 + 1e-16f), i3 = 1.f / (d3 + 1e-16f);
        float iA = hsel ? i1 : i0, iB = hsel ? i3 : i2;
        float cA = hsel ? c1 : c0, cB = hsel ? c3 : c2;
        float aA = hsel ? adv.y : adv.x, aB = hsel ? adv.w : adv.z;

        float accA = 0.f, accB = 0.f;
        for (int idx = s0; idx < s1; idx++) {
            int2 ed = edata[idx];
            float ea = __int_as_float(ed.y);
            float4 av = *(const float4*)&asrc[(size_t)ed.x * 4];
            float wA = cexpf(lrelu((hsel ? av.y : av.x) + aA + ea * cA)) * iA;
            float wB = cexpf(lrelu((hsel ? av.w : av.z) + aB + ea * cB)) * iB;
            u32 hw = hp[(size_t)ed.x * 64 + lane];
            accA += wA * bl(hw);
            accB += wB * bh(hw);
        }
        float rA = fmaxf(accA + biasA, 0.f);
        float rB = fmaxf(accB + biasB, 0.f);
        out[(size_t)d * 64 + lane] = (u32)f2bf(rA) | ((u32)f2bf(rB) << 16);
    }
}

__global__ __launch_bounds__(256) void k_gat2f(
    const u16* __restrict__ h, const float* __restrict__ asrc, const float* __restrict__ adst,
    const int2* __restrict__ edata, const int* __restrict__ roff,
    const int* __restrict__ flag, const float* __restrict__ consts, const void* bias,
    u16* __restrict__ out, int n, int E) {
    int f = *flag;
    int gtid = blockIdx.x * 256 + threadIdx.x;
    int wv = gtid >> 6, lane = gtid & 63;
    int nw = (gridDim.x * 256) >> 6;
    const float C = consts[4];
    const float biasL = load1(bias, lane, f);

    for (int d = wv; d < n; d += nw) {
        int s0 = clampi(roff[d], 0, E);
        int s1 = clampi(roff[d + 1], s0, E);
        float ad = adst[d];
        float den = 0.f;
        for (int idx = s0 + lane; idx < s1; idx += 64) {
            int2 ed = edata[idx];
            den += cexpf(lrelu(asrc[ed.x] + ad + __int_as_float(ed.y) * C));
        }
        #pragma unroll
        for (int off = 32; off > 0; off >>= 1) den += __shfl_xor(den, off);
        float inv = 1.f / (den + 1e-16f);

        float acc = 0.f;
        for (int idx = s0; idx < s1; idx++) {
            int2 ed = edata[idx];
            float w = cexpf(lrelu(asrc[ed.x] + ad + __int_as_float(ed.y) * C)) * inv;
            acc += w * bf2f(h[(size_t)ed.x * 64 + lane]);
        }
        out[(size_t)d * 64 + lane] = f2bf(acc + biasL);
    }
}

// ---------------- pooling ---------------------------------------------------------------
__global__ void k_pool(const u16* __restrict__ agg2, const int* __restrict__ batch,
                       float* __restrict__ pool, float* __restrict__ cnt, int n, int G) {
    int t = blockIdx.x * 256 + threadIdx.x;
    int nb8 = (n + 7) / 8;
    if (t >= nb8 * 64) return;
    int base = (t >> 6) * 8;
    int c = t & 63;
    int end = min(base + 8, n);
    float acc = 0.f, cacc = 0.f;
    int curg = clampi(batch[base], 0, G - 1);
    for (int j = base; j < end; j++) {
        int g = clampi(batch[j], 0, G - 1);
        if (g != curg) {
            atomicAdd(&pool[curg * 64 + c], acc);
            if (c == 0) atomicAdd(&cnt[curg], cacc);
            acc = 0.f; cacc = 0.f; curg = g;
        }
        acc += bf2f(agg2[(size_t)j * 64 + c]);
        cacc += 1.f;
    }
    atomicAdd(&pool[curg * 64 + c], acc);
    if (c == 0) atomicAdd(&cnt[curg], cacc);
}

__global__ void k_head(const float* __restrict__ pool, const float* __restrict__ cnt,
                       const void* Wp, const void* bp, const int* __restrict__ flag,
                       void* out, int G) {
    int f = *flag;
    int g = threadIdx.x;
    if (g >= G) return;
    float s = 0.f;
    for (int c = 0; c < 64; c++) s += pool[g * 64 + c] * load1(Wp, c, f);
    float cv = cnt[g];
    if (!(cv > 0.f)) cv = 1.f;
    float r = s / cv + load1(bp, 0, f);
    if (f) ((float*)out)[g] = r;
    else   ((u16*)out)[g] = f2bf(r);
}

// ---------------- launch ----------------------------------------------------------------
extern "C" void kernel_launch(void* const* d_in, const int* in_sizes, int n_in,
                              void* d_out, int out_size, void* d_ws, size_t ws_size,
                              hipStream_t stream) {
    const void* x    = d_in[0];
    const int* ei    = (const int*)d_in[1];
    const void* eattr = d_in[2];
    const int* batch = (const int*)d_in[3];
    const void* W1   = d_in[4];
    const void* as1  = d_in[5];
    const void* ad1  = d_in[6];
    const void* We1  = d_in[7];
    const void* ae1  = d_in[8];
    const void* b1   = d_in[9];
    const void* W2   = d_in[10];
    const void* as2  = d_in[11];
    const void* ad2  = d_in[12];
    const void* We2  = d_in[13];
    const void* ae2  = d_in[14];
    const void* b2   = d_in[15];
    const void* Wp   = d_in[16];
    const void* bp   = d_in[17];

    const int N = in_sizes[3];
    const int E = in_sizes[2];
    const int G = out_size;
    const int* src = ei;
    const int* dst = ei + E;
    const int B = (N + 255) >> 8;

    char* p = (char*)d_ws;
    auto alloc = [&](size_t bytes) -> char* {
        char* r = p;
        p += (bytes + 255) & ~(size_t)255;
        return r;
    };
    int* flag    = (int*)alloc(32);
    float* consts = (float*)alloc(2048);
    int* roff    = (int*)alloc((size_t)(N + 1) * 4);
    int* rpos    = (int*)alloc((size_t)N * 4);
    int* bsum    = (int*)alloc(256 * 4);
    int* bcnt    = (int*)alloc((size_t)(MAXB * 3 + 1) * 4);
    int* bbase   = bcnt + MAXB;          // B+1 entries
    int* bfront  = bbase + MAXB + 1;     // B entries
    int2* edata  = (int2*)alloc((size_t)E * 8);
    float* pool  = (float*)alloc((size_t)(G * 64 + G) * 4);
    float* cnt   = pool + (size_t)G * 64;
    float* asrc1 = (float*)alloc((size_t)N * 4 * 4);
    float* adst1 = (float*)alloc((size_t)N * 4 * 4);
    float* asrc2 = asrc1;             // alias: dead after gat1
    float* adst2 = adst1;
    u16* agg1    = (u16*)alloc((size_t)N * 128 * 2);
    u16* h1      = (u16*)alloc((size_t)N * 128 * 2);
    u16* h2      = h1;                // alias: h1 dead after gat1
    u16* agg2    = h1 + (size_t)N * 64;
    // al: gat spill buffer (deg>64 only). staged aliases al (temporally disjoint).
    float* al    = (float*)alloc((size_t)E * 16);
    int4* staged = (int4*)al;
    size_t full_need = (size_t)(p - (char*)d_ws);
    const bool cached = (ws_size >= full_need);
    const bool binned = cached && (B <= MAXB);

    hipMemsetAsync(rpos, 0, (size_t)N * 4, stream);
    hipMemsetAsync(bcnt, 0, (size_t)B * 4, stream);
    hipMemsetAsync(pool, 0, (size_t)(G * 64 + G) * 4, stream);

    k_detect<<<1, 64, 0, stream>>>((const u32*)x, flag);
    k_consts<<<1, 256, 0, stream>>>(We1, ae1, We2, ae2, as1, ad1, as2, ad2, flag, consts);
    k_gemmA<<<512, 256, 0, stream>>>(x, W1, flag, (u32*)h1, N);
    k_coef1<<<(N * 2 + 255) / 256, 256, 0, stream>>>((const u32*)h1, consts, asrc1, adst1, N);

    int NB = (N + 255) / 256;
    k_bhist<<<512, 256, 0, stream>>>(dst, rpos, bcnt, E, N, B);
    k_scan1<<<NB, 256, 0, stream>>>(rpos, roff + 1, bsum, N);
    k_scan2<<<1, 256, 0, stream>>>(bsum, NB);
    k_scan3<<<(N + 256) / 256, 256, 0, stream>>>(roff, bsum, rpos, N);
    if (binned) {
        k_bscan<<<1, 64, 0, stream>>>(bcnt, bbase, bfront, B);
        k_binA<<<(E + 2047) / 2048, 256, 0, stream>>>(dst, src, eattr, flag, bfront,
                                                      staged, E, N, B);
        k_binB<<<B, 256, 0, stream>>>(staged, bbase, roff, edata, N, E, B);
    } else {
        k_scatter<<<(E + 255) / 256, 256, 0, stream>>>(dst, src, eattr, flag, rpos,
                                                       edata, E, N);
    }

    int gatBlocks = (N * 64 + 255) / 256;
    if (cached) {
        k_gat1c<<<gatBlocks, 256, 0, stream>>>((const u32*)h1, asrc1, adst1, edata, roff,
                                               flag, consts, b1, al, (u32*)agg1, N, E);
    } else {
        k_gat1f<<<gatBlocks, 256, 0, stream>>>((const u32*)h1, asrc1, adst1, edata, roff,
                                               flag, consts, b1, (u32*)agg1, N, E);
    }
    // gemmB consumes agg1 (paired u32), writes h2 + fused coef2 (asrc2/adst2)
    k_gemmB<<<512, 256, 0, stream>>>((const u32*)agg1, W2, flag, consts,
                                     h2, asrc2, adst2, N);
    if (cached) {
        k_gat2c<<<gatBlocks, 256, 0, stream>>>(h2, asrc2, adst2, edata, roff, flag,
                                               consts, b2, al, agg2, N, E);
    } else {
        k_gat2f<<<gatBlocks, 256, 0, stream>>>(h2, asrc2, adst2, edata, roff, flag,
                                               consts, b2, agg2, N, E);
    }
    k_pool<<<(((N + 7) / 8) * 64 + 255) / 256, 256, 0, stream>>>(agg2, batch, pool, cnt, N, G);
    k_head<<<1, 64, 0, stream>>>(pool, cnt, Wp, bp, flag, d_out, G);
}

// Round 15
// 409.624 us; speedup vs baseline: 1.0409x; 1.0409x over previous
//
#include <hip/hip_runtime.h>
#include <hip/hip_bf16.h>

typedef unsigned short u16;
typedef unsigned int u32;

#define MAXB 2048

__device__ __forceinline__ float bf2f(u16 u) { return __uint_as_float(((u32)u) << 16); }
__device__ __forceinline__ float bl(u32 u) { return __uint_as_float(u << 16); }
__device__ __forceinline__ float bh(u32 u) { return __uint_as_float(u & 0xffff0000u); }
__device__ __forceinline__ u16 f2bf(float f) {
    u32 u = __float_as_uint(f);
    u += 0x7fffu + ((u >> 16) & 1u);   // round-to-nearest-even
    return (u16)(u >> 16);
}
__device__ __forceinline__ float lrelu(float x) { return x > 0.f ? x : 0.2f * x; }
__device__ __forceinline__ int clampi(int v, int lo, int hi) {
    return v < lo ? lo : (v > hi ? hi : v);
}
__device__ __forceinline__ float load1(const void* base, int idx, int f32) {
    return f32 ? ((const float*)base)[idx] : bf2f(((const u16*)base)[idx]);
}
// softmax without max-shift: clamp keeps exp finite; shift-invariance => same ratios
__device__ __forceinline__ float cexpf(float a) { return expf(fminf(a, 30.f)); }

// ---------------- dtype detector (+ fold: zero bcnt) -------------------------------------
__global__ void k_detect(const u32* __restrict__ xw, int* __restrict__ flag,
                         int* __restrict__ bcnt, int B) {
    int lane = threadIdx.x & 63;
    for (int i = lane; i < B; i += 64) bcnt[i] = 0;
    int cnt = 0;
    #pragma unroll
    for (int j = 0; j < 4; j++) {
        u32 w = xw[lane * 4 + j];
        int e0 = (int)((w >> 7) & 0xffu);
        int e1 = (int)((w >> 23) & 0xffu);
        cnt += (e0 >= 0x60 && e0 <= 0x8f);
        cnt += (e1 >= 0x60 && e1 <= 0x8f);
    }
    #pragma unroll
    for (int off = 32; off > 0; off >>= 1) cnt += __shfl_xor(cnt, off);
    if (lane == 0) *flag = (cnt < 480) ? 1 : 0;
}

// ---------------- constants (+ fold: zero pool) ------------------------------------------
__global__ void k_consts(const void* We1, const void* ae1, const void* We2, const void* ae2,
                         const void* as1, const void* ad1, const void* as2, const void* ad2,
                         const int* __restrict__ flag, float* __restrict__ consts,
                         float* __restrict__ pool, int psize) {
    int f = *flag;
    int t = threadIdx.x;
    for (int i = t; i < psize; i += 256) pool[i] = 0.f;
    if (t < 4) {
        float s = 0.f;
        for (int c = 0; c < 32; c++) s += load1(We1, t * 32 + c, f) * load1(ae1, t * 32 + c, f);
        consts[t] = s;
    } else if (t == 4) {
        float s = 0.f;
        for (int c = 0; c < 64; c++) s += load1(We2, c, f) * load1(ae2, c, f);
        consts[4] = s;
    }
    if (t < 128) {
        consts[8 + t] = load1(as1, t, f);
        consts[136 + t] = load1(ad1, t, f);
    }
    if (t < 64) {
        consts[264 + t] = load1(as2, t, f);
        consts[328 + t] = load1(ad2, t, f);
    }
}

// ---------------- GEMM: Y[nrows,NC] = X[nrows,128] @ W[128,NC] (R13-proven) -------------
template <int NC>
__global__ __launch_bounds__(256, 4) void k_gemm5(
    const void* __restrict__ X, const void* __restrict__ Wg,
    const int* __restrict__ flag, int fXovr, u16* __restrict__ Y, int nrows) {
    constexpr int K = 128;
    constexpr int ROWS = 32;
    __shared__ float Ws[K * NC];
    __shared__ float Xs[ROWS * K];

    const int f = *flag;
    const bool fX = (fXovr < 0) ? (f != 0) : (fXovr != 0);
    const bool fW = (f != 0);
    const int tid = threadIdx.x, wid = tid >> 6, lane = tid & 63;

    for (int i = tid * 4; i < K * NC; i += 256 * 4) {
        int j = i / NC;
        int col = i & (NC - 1);
        int srow = (NC == 64) ? ((j & 1) * 64 + (j >> 1)) : j;
        int g = srow * NC + col;
        if (fW) {
            float4 v = *(const float4*)((const float*)Wg + g);
            Ws[i] = v.x; Ws[i + 1] = v.y; Ws[i + 2] = v.z; Ws[i + 3] = v.w;
        } else {
            ushort4 r = *(const ushort4*)((const u16*)Wg + g);
            Ws[i] = bf2f(r.x); Ws[i + 1] = bf2f(r.y);
            Ws[i + 2] = bf2f(r.z); Ws[i + 3] = bf2f(r.w);
        }
    }

    const int sr = tid >> 3;
    const int sc = (tid & 7) * 16;

    for (int base = blockIdx.x * ROWS; base < nrows; base += gridDim.x * ROWS) {
        __syncthreads();
        {
            int row = base + sr;
            float* xs = &Xs[sr * K + sc];
            if (row < nrows) {
                if (fX) {
                    const float* xp = (const float*)X + (size_t)row * K + sc;
                    float4 a = *(const float4*)xp;
                    float4 b = *(const float4*)(xp + 4);
                    float4 c = *(const float4*)(xp + 8);
                    float4 d = *(const float4*)(xp + 12);
                    xs[0] = a.x; xs[1] = a.y; xs[2] = a.z; xs[3] = a.w;
                    xs[4] = b.x; xs[5] = b.y; xs[6] = b.z; xs[7] = b.w;
                    xs[8] = c.x; xs[9] = c.y; xs[10] = c.z; xs[11] = c.w;
                    xs[12] = d.x; xs[13] = d.y; xs[14] = d.z; xs[15] = d.w;
                } else {
                    const u16* xp = (const u16*)X + (size_t)row * K + sc;
                    uint4 a = *(const uint4*)xp;
                    uint4 b = *(const uint4*)(xp + 8);
                    xs[0] = bl(a.x); xs[1] = bh(a.x); xs[2] = bl(a.y); xs[3] = bh(a.y);
                    xs[4] = bl(a.z); xs[5] = bh(a.z); xs[6] = bl(a.w); xs[7] = bh(a.w);
                    xs[8] = bl(b.x); xs[9] = bh(b.x); xs[10] = bl(b.y); xs[11] = bh(b.y);
                    xs[12] = bl(b.z); xs[13] = bh(b.z); xs[14] = bl(b.w); xs[15] = bh(b.w);
                }
            } else {
                #pragma unroll
                for (int j = 0; j < 16; j++) xs[j] = 0.f;
            }
        }
        __syncthreads();

        float acc0[8] = {0.f, 0.f, 0.f, 0.f, 0.f, 0.f, 0.f, 0.f};
        float acc1[8] = {0.f, 0.f, 0.f, 0.f, 0.f, 0.f, 0.f, 0.f};
        #pragma unroll 2
        for (int k = 0; k < K; k += 4) {
            float wa0 = Ws[(k + 0) * NC + lane];
            float wa1 = Ws[(k + 1) * NC + lane];
            float wa2 = Ws[(k + 2) * NC + lane];
            float wa3 = Ws[(k + 3) * NC + lane];
            float wb0 = 0.f, wb1 = 0.f, wb2 = 0.f, wb3 = 0.f;
            if constexpr (NC == 128) {
                wb0 = Ws[(k + 0) * NC + lane + 64];
                wb1 = Ws[(k + 1) * NC + lane + 64];
                wb2 = Ws[(k + 2) * NC + lane + 64];
                wb3 = Ws[(k + 3) * NC + lane + 64];
            }
            #pragma unroll
            for (int rr = 0; rr < 8; rr++) {
                float4 xv = *(const float4*)&Xs[(wid * 8 + rr) * K + k];
                acc0[rr] += xv.x * wa0 + xv.y * wa1 + xv.z * wa2 + xv.w * wa3;
                if constexpr (NC == 128)
                    acc1[rr] += xv.x * wb0 + xv.y * wb1 + xv.z * wb2 + xv.w * wb3;
            }
        }

        #pragma unroll
        for (int rr = 0; rr < 8; rr++) {
            int row = base + wid * 8 + rr;
            if (row < nrows) {
                if constexpr (NC == 128) {
                    u32 w = (u32)f2bf(acc0[rr]) | ((u32)f2bf(acc1[rr]) << 16);
                    ((u32*)Y)[(size_t)row * 64 + lane] = w;
                } else {
                    Y[(size_t)row * 64 + lane] = f2bf(acc0[rr]);
                }
            }
        }
    }
}

// ---------------- coef1: paired h1 -> asrc1/adst1 [N][4] (+ fold: zero rpos) ------------
__global__ void k_coef1(const u32* __restrict__ hp, const float* __restrict__ consts,
                        float* __restrict__ asrc, float* __restrict__ adst,
                        int* __restrict__ rpos, int n) {
    int i = blockIdx.x * 256 + threadIdx.x;
    if (i < n) rpos[i] = 0;
    if (i >= n * 2) return;
    int node = i >> 1, g = i & 1;
    const u32* w = hp + (size_t)node * 64 + g * 32;
    const float* asA = consts + 8 + g * 32;
    const float* adA = consts + 136 + g * 32;
    const float* asB = consts + 8 + (g + 2) * 32;
    const float* adB = consts + 136 + (g + 2) * 32;
    float sA1 = 0.f, sA2 = 0.f, sB1 = 0.f, sB2 = 0.f;
    #pragma unroll
    for (int c = 0; c < 32; c += 4) {
        uint4 q = *(const uint4*)&w[c];
        float l0 = bl(q.x), h0 = bh(q.x), l1 = bl(q.y), h1 = bh(q.y);
        float l2 = bl(q.z), h2 = bh(q.z), l3 = bl(q.w), h3 = bh(q.w);
        sA1 += l0 * asA[c] + l1 * asA[c + 1] + l2 * asA[c + 2] + l3 * asA[c + 3];
        sA2 += l0 * adA[c] + l1 * adA[c + 1] + l2 * adA[c + 2] + l3 * adA[c + 3];
        sB1 += h0 * asB[c] + h1 * asB[c + 1] + h2 * asB[c + 2] + h3 * asB[c + 3];
        sB2 += h0 * adB[c] + h1 * adB[c + 1] + h2 * adB[c + 2] + h3 * adB[c + 3];
    }
    asrc[node * 4 + g] = sA1;     adst[node * 4 + g] = sA2;
    asrc[node * 4 + g + 2] = sB1; adst[node * 4 + g + 2] = sB2;
}

// ---------------- coef2: natural h2 -> asrc2/adst2 [N] ----------------------------------
__global__ void k_coef2(const u32* __restrict__ hp, const float* __restrict__ consts,
                        float* __restrict__ asrc, float* __restrict__ adst, int n) {
    int i = blockIdx.x * 256 + threadIdx.x;
    if (i >= n) return;
    const u32* w = hp + (size_t)i * 32;
    const float* as_ = consts + 264;
    const float* ad_ = consts + 328;
    float s1 = 0.f, s2 = 0.f;
    #pragma unroll
    for (int c = 0; c < 32; c += 4) {
        uint4 q = *(const uint4*)&w[c];
        float l0 = bl(q.x), h0 = bh(q.x), l1 = bl(q.y), h1 = bh(q.y);
        float l2 = bl(q.z), h2 = bh(q.z), l3 = bl(q.w), h3 = bh(q.w);
        s1 += l0 * as_[2*c] + h0 * as_[2*c+1] + l1 * as_[2*c+2] + h1 * as_[2*c+3]
            + l2 * as_[2*c+4] + h2 * as_[2*c+5] + l3 * as_[2*c+6] + h3 * as_[2*c+7];
        s2 += l0 * ad_[2*c] + h0 * ad_[2*c+1] + l1 * ad_[2*c+2] + h1 * ad_[2*c+3]
            + l2 * ad_[2*c+4] + h2 * ad_[2*c+5] + l3 * ad_[2*c+6] + h3 * ad_[2*c+7];
    }
    asrc[i] = s1; adst[i] = s2;
}

// ---------------- CSR build -------------------------------------------------------------
__global__ __launch_bounds__(256) void k_bhist(const int* __restrict__ dst,
                                               int* __restrict__ cnt, int* __restrict__ bcnt,
                                               int E, int n, int B) {
    __shared__ int lh[MAXB];
    for (int i = threadIdx.x; i < B; i += 256) lh[i] = 0;
    __syncthreads();
    int stride = gridDim.x * 256;
    for (int e = blockIdx.x * 256 + threadIdx.x; e < E; e += stride) {
        int d = clampi(dst[e], 0, n - 1);
        atomicAdd(&cnt[d], 1);
        atomicAdd(&lh[d >> 8], 1);
    }
    __syncthreads();
    for (int i = threadIdx.x; i < B; i += 256)
        if (lh[i]) atomicAdd(&bcnt[i], lh[i]);
}
// scan1 (+ fold: serial bucket scan on block 0 / thread 0 — bcnt complete after bhist)
__global__ void k_scan1(const int* __restrict__ cnt, int* __restrict__ part,
                        int* __restrict__ bsum, int n,
                        const int* __restrict__ bcnt, int* __restrict__ bbase,
                        int* __restrict__ bfront, int B, int dob) {
    __shared__ int buf[256];
    int i = blockIdx.x * 256 + threadIdx.x;
    if (dob && blockIdx.x == 0 && threadIdx.x == 255) {
        int acc = 0;
        for (int k = 0; k < B; k++) { bbase[k] = acc; bfront[k] = acc; acc += bcnt[k]; }
        bbase[B] = acc;
    }
    int v = (i < n) ? cnt[i] : 0;
    buf[threadIdx.x] = v;
    __syncthreads();
    for (int off = 1; off < 256; off <<= 1) {
        int t = (threadIdx.x >= off) ? buf[threadIdx.x - off] : 0;
        __syncthreads();
        buf[threadIdx.x] += t;
        __syncthreads();
    }
    if (i < n) part[i] = buf[threadIdx.x];
    if (threadIdx.x == 255) bsum[blockIdx.x] = buf[255];
}
// scan3b: merged scan2+scan3 — each block re-scans the block sums in LDS
__global__ void k_scan3b(int* __restrict__ roff, const int* __restrict__ bsum,
                         int* __restrict__ rpos, int n, int nb) {
    __shared__ int buf[256];
    int t = threadIdx.x;
    int v = (t < nb) ? bsum[t] : 0;
    buf[t] = v;
    __syncthreads();
    for (int off = 1; off < 256; off <<= 1) {
        int u = (t >= off) ? buf[t - off] : 0;
        __syncthreads();
        buf[t] += u;
        __syncthreads();
    }
    __shared__ int excl[256];
    excl[t] = buf[t] - v;   // exclusive prefix of bsum
    __syncthreads();
    int i = blockIdx.x * 256 + t;
    if (i > n) return;
    int val;
    if (i == 0) { val = 0; roff[0] = 0; }
    else { val = roff[i] + excl[(i - 1) >> 8]; roff[i] = val; }
    if (i < n) rpos[i] = val;
}
// binA: tile-ranked bucket scatter -> staged int4 {src, dst, ea_bits, 0}
__global__ __launch_bounds__(256) void k_binA(
    const int* __restrict__ dst, const int* __restrict__ src, const void* eattr,
    const int* __restrict__ flag, int* __restrict__ bfront, int4* __restrict__ staged,
    int E, int n, int B) {
    __shared__ int lhist[MAXB];
    __shared__ int lbase[MAXB];
    int f = *flag;
    constexpr int T = 2048;
    for (int tile = blockIdx.x; (long long)tile * T < E; tile += gridDim.x) {
        int base = tile * T;
        for (int i = threadIdx.x; i < B; i += 256) lhist[i] = 0;
        __syncthreads();
        int sj0, sj1, sj2, sj3, sj4, sj5, sj6, sj7;
        int dj0, dj1, dj2, dj3, dj4, dj5, dj6, dj7;
        int rj0, rj1, rj2, rj3, rj4, rj5, rj6, rj7;
        int ej0, ej1, ej2, ej3, ej4, ej5, ej6, ej7;
        #define BINA_LOAD(J, SJ, DJ, RJ, EJ)                                   \
        {                                                                      \
            int idx = base + (J) * 256 + threadIdx.x;                          \
            bool v = idx < E;                                                  \
            int d = v ? clampi(dst[idx], 0, n - 1) : 0;                        \
            SJ = v ? clampi(src[idx], 0, n - 1) : 0;                           \
            EJ = v ? __float_as_int(load1(eattr, idx, f)) : 0;                 \
            DJ = d;                                                            \
            RJ = v ? atomicAdd(&lhist[d >> 8], 1) : -1;                        \
        }
        BINA_LOAD(0, sj0, dj0, rj0, ej0)
        BINA_LOAD(1, sj1, dj1, rj1, ej1)
        BINA_LOAD(2, sj2, dj2, rj2, ej2)
        BINA_LOAD(3, sj3, dj3, rj3, ej3)
        BINA_LOAD(4, sj4, dj4, rj4, ej4)
        BINA_LOAD(5, sj5, dj5, rj5, ej5)
        BINA_LOAD(6, sj6, dj6, rj6, ej6)
        BINA_LOAD(7, sj7, dj7, rj7, ej7)
        #undef BINA_LOAD
        __syncthreads();
        for (int i = threadIdx.x; i < B; i += 256) {
            int c = lhist[i];
            lbase[i] = c ? atomicAdd(&bfront[i], c) : 0;
        }
        __syncthreads();
        #define BINA_STORE(SJ, DJ, RJ, EJ)                                     \
        if (RJ >= 0) {                                                         \
            long long q = (long long)lbase[DJ >> 8] + RJ;                      \
            if (q >= 0 && q < E) {                                             \
                int4 v; v.x = SJ; v.y = DJ; v.z = EJ; v.w = 0;                 \
                staged[q] = v;                                                 \
            }                                                                  \
        }
        BINA_STORE(sj0, dj0, rj0, ej0)
        BINA_STORE(sj1, dj1, rj1, ej1)
        BINA_STORE(sj2, dj2, rj2, ej2)
        BINA_STORE(sj3, dj3, rj3, ej3)
        BINA_STORE(sj4, dj4, rj4, ej4)
        BINA_STORE(sj5, dj5, rj5, ej5)
        BINA_STORE(sj6, dj6, rj6, ej6)
        BINA_STORE(sj7, dj7, rj7, ej7)
        #undef BINA_STORE
        __syncthreads();
    }
}
// binB: one workgroup per bucket; writes confined to the bucket's edata window
__global__ __launch_bounds__(256) void k_binB(
    const int4* __restrict__ staged, const int* __restrict__ bbase,
    const int* __restrict__ roff, int2* __restrict__ edata, int N, int E, int B) {
    __shared__ int lpos[256];
    int k = blockIdx.x;
    int dlo = k << 8;
    int t = threadIdx.x;
    int dn = dlo + t;
    lpos[t] = (dn < N) ? roff[dn] : 0;
    __syncthreads();
    int lo = clampi(bbase[k], 0, E);
    int hi = clampi(bbase[k + 1], lo, E);
    for (int i = lo + t; i < hi; i += 256) {
        int4 v = staged[i];
        int p = atomicAdd(&lpos[v.y & 255], 1);
        if (p >= 0 && p < E) edata[p] = make_int2(v.x, v.z);
    }
}
// fallback single-pass scatter
__global__ void k_scatter(const int* __restrict__ dst, const int* __restrict__ src,
                          const void* eattr, const int* __restrict__ flag,
                          int* __restrict__ rpos, int2* __restrict__ edata, int E, int n) {
    int f = *flag;
    int e = blockIdx.x * 256 + threadIdx.x;
    if (e < E) {
        int d = clampi(dst[e], 0, n - 1);
        int s = clampi(src[e], 0, n - 1);
        float ea = load1(eattr, e, f);
        int p = atomicAdd(&rpos[d], 1);
        if (p >= 0 && p < E) {
            int2 v; v.x = s; v.y = __float_as_int(ea);
            edata[p] = v;
        }
    }
}

// ---------------- gat1, CACHED: fused fast path, no-max softmax, LDS weights, 4x MLP ----
__global__ __launch_bounds__(256) void k_gat1c(
    const u32* __restrict__ hp, const float* __restrict__ asrc, const float* __restrict__ adst,
    const int2* __restrict__ edata, const int* __restrict__ roff,
    const int* __restrict__ flag, const float* __restrict__ consts, const void* bias,
    float* __restrict__ al, u32* __restrict__ out, int n, int E) {
    __shared__ float4 wls[4][64];
    int f = *flag;
    int gtid = blockIdx.x * 256 + threadIdx.x;
    int wv = gtid >> 6, lane = gtid & 63;
    int wid = (threadIdx.x >> 6);
    int nw = (gridDim.x * 256) >> 6;
    const float c0 = consts[0], c1 = consts[1], c2 = consts[2], c3 = consts[3];
    const int hsel = lane >> 5;
    const float biasA = load1(bias, lane, f);
    const float biasB = load1(bias, 64 + lane, f);

    for (int d = wv; d < n; d += nw) {
        int s0 = clampi(roff[d], 0, E);
        int s1 = clampi(roff[d + 1], s0, E);
        int deg = s1 - s0;
        float4 adv = *(const float4*)&adst[d * 4];
        float accA = 0.f, accB = 0.f;

        if (deg <= 64) {
            bool v = lane < deg;
            int s = 0;
            float e0 = 0.f, e1 = 0.f, e2 = 0.f, e3 = 0.f;
            if (v) {
                int2 ed = edata[s0 + lane];
                s = ed.x;
                float ea = __int_as_float(ed.y);
                float4 av = *(const float4*)&asrc[(size_t)s * 4];
                e0 = cexpf(lrelu(av.x + adv.x + ea * c0));
                e1 = cexpf(lrelu(av.y + adv.y + ea * c1));
                e2 = cexpf(lrelu(av.z + adv.z + ea * c2));
                e3 = cexpf(lrelu(av.w + adv.w + ea * c3));
            }
            float d0 = e0, d1 = e1, d2 = e2, d3 = e3;
            #pragma unroll
            for (int off = 32; off > 0; off >>= 1) {
                d0 += __shfl_xor(d0, off); d1 += __shfl_xor(d1, off);
                d2 += __shfl_xor(d2, off); d3 += __shfl_xor(d3, off);
            }
            float i0 = 1.f / (d0 + 1e-16f), i1 = 1.f / (d1 + 1e-16f);
            float i2 = 1.f / (d2 + 1e-16f), i3 = 1.f / (d3 + 1e-16f);
            if (v) wls[wid][lane] = make_float4(e0 * i0, e1 * i1, e2 * i2, e3 * i3);

            int j = 0;
            for (; j + 4 <= deg; j += 4) {
                int sa = __shfl(s, j), sb = __shfl(s, j + 1);
                int sc_ = __shfl(s, j + 2), sd = __shfl(s, j + 3);
                u32 ha = hp[(size_t)sa * 64 + lane];
                u32 hb = hp[(size_t)sb * 64 + lane];
                u32 hc = hp[(size_t)sc_ * 64 + lane];
                u32 hd = hp[(size_t)sd * 64 + lane];
                float4 wa = wls[wid][j], wb = wls[wid][j + 1];
                float4 wc = wls[wid][j + 2], wd = wls[wid][j + 3];
                accA += (hsel ? wa.y : wa.x) * bl(ha); accB += (hsel ? wa.w : wa.z) * bh(ha);
                accA += (hsel ? wb.y : wb.x) * bl(hb); accB += (hsel ? wb.w : wb.z) * bh(hb);
                accA += (hsel ? wc.y : wc.x) * bl(hc); accB += (hsel ? wc.w : wc.z) * bh(hc);
                accA += (hsel ? wd.y : wd.x) * bl(hd); accB += (hsel ? wd.w : wd.z) * bh(hd);
            }
            for (; j < deg; j++) {
                int sj = __shfl(s, j);
                u32 hw = hp[(size_t)sj * 64 + lane];
                float4 w = wls[wid][j];
                accA += (hsel ? w.y : w.x) * bl(hw);
                accB += (hsel ? w.w : w.z) * bh(hw);
            }
        } else {
            // general path (rare): 2 passes (exp+sum, then weighted gather)
            float d0 = 0.f, d1 = 0.f, d2 = 0.f, d3 = 0.f;
            for (int idx = s0 + lane; idx < s1; idx += 64) {
                int2 ed = edata[idx];
                int s = ed.x;
                float ea = __int_as_float(ed.y);
                float4 av = *(const float4*)&asrc[(size_t)s * 4];
                float e0 = cexpf(lrelu(av.x + adv.x + ea * c0));
                float e1 = cexpf(lrelu(av.y + adv.y + ea * c1));
                float e2 = cexpf(lrelu(av.z + adv.z + ea * c2));
                float e3 = cexpf(lrelu(av.w + adv.w + ea * c3));
                *(float4*)&al[(size_t)idx * 4] = make_float4(e0, e1, e2, e3);
                d0 += e0; d1 += e1; d2 += e2; d3 += e3;
            }
            #pragma unroll
            for (int off = 32; off > 0; off >>= 1) {
                d0 += __shfl_xor(d0, off); d1 += __shfl_xor(d1, off);
                d2 += __shfl_xor(d2, off); d3 += __shfl_xor(d3, off);
            }
            float i0 = 1.f / (d0 + 1e-16f), i1 = 1.f / (d1 + 1e-16f);
            float i2 = 1.f / (d2 + 1e-16f), i3 = 1.f / (d3 + 1e-16f);
            float iA = hsel ? i1 : i0, iB = hsel ? i3 : i2;
            for (int idx = s0; idx < s1; idx++) {
                int s = edata[idx].x;
                float4 ex = *(const float4*)&al[(size_t)idx * 4];
                float wA = (hsel ? ex.y : ex.x) * iA;
                float wB = (hsel ? ex.w : ex.z) * iB;
                u32 hw = hp[(size_t)s * 64 + lane];
                accA += wA * bl(hw);
                accB += wB * bh(hw);
            }
        }
        float rA = fmaxf(accA + biasA, 0.f);   // fused ReLU
        float rB = fmaxf(accB + biasB, 0.f);
        out[(size_t)d * 64 + lane] = (u32)f2bf(rA) | ((u32)f2bf(rB) << 16);
    }
}

// ---------------- gat2, CACHED: fused fast path, no-max softmax -------------------------
__global__ __launch_bounds__(256) void k_gat2c(
    const u16* __restrict__ h, const float* __restrict__ asrc, const float* __restrict__ adst,
    const int2* __restrict__ edata, const int* __restrict__ roff,
    const int* __restrict__ flag, const float* __restrict__ consts, const void* bias,
    float* __restrict__ al, u16* __restrict__ out, int n, int E) {
    __shared__ float wls[4][64];
    int f = *flag;
    int gtid = blockIdx.x * 256 + threadIdx.x;
    int wv = gtid >> 6, lane = gtid & 63;
    int wid = (threadIdx.x >> 6);
    int nw = (gridDim.x * 256) >> 6;
    const float C = consts[4];
    const float biasL = load1(bias, lane, f);

    for (int d = wv; d < n; d += nw) {
        int s0 = clampi(roff[d], 0, E);
        int s1 = clampi(roff[d + 1], s0, E);
        int deg = s1 - s0;
        float ad = adst[d];
        float acc = 0.f;

        if (deg <= 64) {
            bool v = lane < deg;
            int s = 0;
            float e = 0.f;
            if (v) {
                int2 ed = edata[s0 + lane];
                s = ed.x;
                e = cexpf(lrelu(asrc[s] + ad + __int_as_float(ed.y) * C));
            }
            float den = e;
            #pragma unroll
            for (int off = 32; off > 0; off >>= 1) den += __shfl_xor(den, off);
            float inv = 1.f / (den + 1e-16f);
            if (v) wls[wid][lane] = e * inv;

            int j = 0;
            for (; j + 4 <= deg; j += 4) {
                int sa = __shfl(s, j), sb = __shfl(s, j + 1);
                int sc_ = __shfl(s, j + 2), sd = __shfl(s, j + 3);
                float ha = bf2f(h[(size_t)sa * 64 + lane]);
                float hb = bf2f(h[(size_t)sb * 64 + lane]);
                float hc = bf2f(h[(size_t)sc_ * 64 + lane]);
                float hd = bf2f(h[(size_t)sd * 64 + lane]);
                acc += wls[wid][j] * ha + wls[wid][j + 1] * hb
                     + wls[wid][j + 2] * hc + wls[wid][j + 3] * hd;
            }
            for (; j < deg; j++) {
                int sj = __shfl(s, j);
                acc += wls[wid][j] * bf2f(h[(size_t)sj * 64 + lane]);
            }
        } else {
            float den = 0.f;
            for (int idx = s0 + lane; idx < s1; idx += 64) {
                int2 ed = edata[idx];
                float e = cexpf(lrelu(asrc[ed.x] + ad + __int_as_float(ed.y) * C));
                al[idx] = e;
                den += e;
            }
            #pragma unroll
            for (int off = 32; off > 0; off >>= 1) den += __shfl_xor(den, off);
            float inv = 1.f / (den + 1e-16f);
            for (int idx = s0; idx < s1; idx++) {
                int s = edata[idx].x;
                acc += al[idx] * inv * bf2f(h[(size_t)s * 64 + lane]);
            }
        }
        out[(size_t)d * 64 + lane] = f2bf(acc + biasL);
    }
}

// ---------------- gat1/gat2 FALLBACK (recompute, no al cache) ---------------------------
__global__ __launch_bounds__(256) void k_gat1f(
    const u32* __restrict__ hp, const float* __restrict__ asrc, const float* __restrict__ adst,
    const int2* __restrict__ edata, const int* __restrict__ roff,
    const int* __restrict__ flag, const float* __restrict__ consts, const void* bias,
    u32* __restrict__ out, int n, int E) {
    int f = *flag;
    int gtid = blockIdx.x * 256 + threadIdx.x;
    int wv = gtid >> 6, lane = gtid & 63;
    int nw = (gridDim.x * 256) >> 6;
    const float c0 = consts[0], c1 = consts[1], c2 = consts[2], c3 = consts[3];
    const int hsel = lane >> 5;
    const float biasA = load1(bias, lane, f);
    const float biasB = load1(bias, 64 + lane, f);

    for (int d = wv; d < n; d += nw) {
        int s0 = clampi(roff[d], 0, E);
        int s1 = clampi(roff[d + 1], s0, E);
        float4 adv = *(const float4*)&adst[d * 4];
        float d0 = 0.f, d1 = 0.f, d2 = 0.f, d3 = 0.f;
        for (int idx = s0 + lane; idx < s1; idx += 64) {
            int2 ed = edata[idx];
            float ea = __int_as_float(ed.y);
            float4 av = *(const float4*)&asrc[(size_t)ed.x * 4];
            d0 += cexpf(lrelu(av.x + adv.x + ea * c0));
            d1 += cexpf(lrelu(av.y + adv.y + ea * c1));
            d2 += cexpf(lrelu(av.z + adv.z + ea * c2));
            d3 += cexpf(lrelu(av.w + adv.w + ea * c3));
        }
        #pragma unroll
        for (int off = 32; off > 0; off >>= 1) {
            d0 += __shfl_xor(d0, off); d1 += __shfl_xor(d1, off);
            d2 += __shfl_xor(d2, off); d3 += __shfl_xor(d3, off);
        }
        float i0 = 1.f / (d0 + 1e-16f), i1 = 1.f / (d1 + 1e-16f);
        float i2 = 1.f / (d2 + 1e-16f), i3 = 1.f / (d3 + 1e-16f);
        float iA = hsel ? i1 : i0, iB = hsel ? i3 : i2;
        float cA = hsel ? c1 : c0, cB = hsel ? c3 : c2;
        float aA = hsel ? adv.y : adv.x, aB = hsel ? adv.w : adv.z;

        float accA = 0.f, accB = 0.f;
        for (int idx = s0; idx < s1; idx++) {
            int2 ed = edata[idx];
            float ea = __int_as_float(ed.y);
            float4 av = *(const float4*)&asrc[(size_t)ed.x * 4];
            float wA = cexpf(lrelu((hsel ? av.y : av.x) + aA + ea * cA)) * iA;
            float wB = cexpf(lrelu((hsel ? av.w : av.z) + aB + ea * cB)) * iB;
            u32 hw = hp[(size_t)ed.x * 64 + lane];
            accA += wA * bl(hw);
            accB += wB * bh(hw);
        }
        float rA = fmaxf(accA + biasA, 0.f);
        float rB = fmaxf(accB + biasB, 0.f);
        out[(size_t)d * 64 + lane] = (u32)f2bf(rA) | ((u32)f2bf(rB) << 16);
    }
}

__global__ __launch_bounds__(256) void k_gat2f(
    const u16* __restrict__ h, const float* __restrict__ asrc, const float* __restrict__ adst,
    const int2* __restrict__ edata, const int* __restrict__ roff,
    const int* __restrict__ flag, const float* __restrict__ consts, const void* bias,
    u16* __restrict__ out, int n, int E) {
    int f = *flag;
    int gtid = blockIdx.x * 256 + threadIdx.x;
    int wv = gtid >> 6, lane = gtid & 63;
    int nw = (gridDim.x * 256) >> 6;
    const float C = consts[4];
    const float biasL = load1(bias, lane, f);

    for (int d = wv; d < n; d += nw) {
        int s0 = clampi(roff[d], 0, E);
        int s1 = clampi(roff[d + 1], s0, E);
        float ad = adst[d];
        float den = 0.f;
        for (int idx = s0 + lane; idx < s1; idx += 64) {
            int2 ed = edata[idx];
            den += cexpf(lrelu(asrc[ed.x] + ad + __int_as_float(ed.y) * C));
        }
        #pragma unroll
        for (int off = 32; off > 0; off >>= 1) den += __shfl_xor(den, off);
        float inv = 1.f / (den + 1e-16f);

        float acc = 0.f;
        for (int idx = s0; idx < s1; idx++) {
            int2 ed = edata[idx];
            float w = cexpf(lrelu(asrc[ed.x] + ad + __int_as_float(ed.y) * C)) * inv;
            acc += w * bf2f(h[(size_t)ed.x * 64 + lane]);
        }
        out[(size_t)d * 64 + lane] = f2bf(acc + biasL);
    }
}

// ---------------- pooling ---------------------------------------------------------------
__global__ void k_pool(const u16* __restrict__ agg2, const int* __restrict__ batch,
                       float* __restrict__ pool, float* __restrict__ cnt, int n, int G) {
    int t = blockIdx.x * 256 + threadIdx.x;
    int nb8 = (n + 7) / 8;
    if (t >= nb8 * 64) return;
    int base = (t >> 6) * 8;
    int c = t & 63;
    int end = min(base + 8, n);
    float acc = 0.f, cacc = 0.f;
    int curg = clampi(batch[base], 0, G - 1);
    for (int j = base; j < end; j++) {
        int g = clampi(batch[j], 0, G - 1);
        if (g != curg) {
            atomicAdd(&pool[curg * 64 + c], acc);
            if (c == 0) atomicAdd(&cnt[curg], cacc);
            acc = 0.f; cacc = 0.f; curg = g;
        }
        acc += bf2f(agg2[(size_t)j * 64 + c]);
        cacc += 1.f;
    }
    atomicAdd(&pool[curg * 64 + c], acc);
    if (c == 0) atomicAdd(&cnt[curg], cacc);
}

__global__ void k_head(const float* __restrict__ pool, const float* __restrict__ cnt,
                       const void* Wp, const void* bp, const int* __restrict__ flag,
                       void* out, int G) {
    int f = *flag;
    int g = threadIdx.x;
    if (g >= G) return;
    float s = 0.f;
    for (int c = 0; c < 64; c++) s += pool[g * 64 + c] * load1(Wp, c, f);
    float cv = cnt[g];
    if (!(cv > 0.f)) cv = 1.f;
    float r = s / cv + load1(bp, 0, f);
    if (f) ((float*)out)[g] = r;
    else   ((u16*)out)[g] = f2bf(r);
}

// ---------------- launch ----------------------------------------------------------------
extern "C" void kernel_launch(void* const* d_in, const int* in_sizes, int n_in,
                              void* d_out, int out_size, void* d_ws, size_t ws_size,
                              hipStream_t stream) {
    const void* x    = d_in[0];
    const int* ei    = (const int*)d_in[1];
    const void* eattr = d_in[2];
    const int* batch = (const int*)d_in[3];
    const void* W1   = d_in[4];
    const void* as1  = d_in[5];
    const void* ad1  = d_in[6];
    const void* We1  = d_in[7];
    const void* ae1  = d_in[8];
    const void* b1   = d_in[9];
    const void* W2   = d_in[10];
    const void* as2  = d_in[11];
    const void* ad2  = d_in[12];
    const void* We2  = d_in[13];
    const void* ae2  = d_in[14];
    const void* b2   = d_in[15];
    const void* Wp   = d_in[16];
    const void* bp   = d_in[17];

    const int N = in_sizes[3];
    const int E = in_sizes[2];
    const int G = out_size;
    const int* src = ei;
    const int* dst = ei + E;
    const int B = (N + 255) >> 8;

    char* p = (char*)d_ws;
    auto alloc = [&](size_t bytes) -> char* {
        char* r = p;
        p += (bytes + 255) & ~(size_t)255;
        return r;
    };
    int* flag    = (int*)alloc(32);
    float* consts = (float*)alloc(2048);
    int* roff    = (int*)alloc((size_t)(N + 1) * 4);
    int* rpos    = (int*)alloc((size_t)N * 4);
    int* bsum    = (int*)alloc(256 * 4);
    int* bcnt    = (int*)alloc((size_t)(MAXB * 3 + 1) * 4);
    int* bbase   = bcnt + MAXB;          // B+1 entries
    int* bfront  = bbase + MAXB + 1;     // B entries
    int2* edata  = (int2*)alloc((size_t)E * 8);
    float* pool  = (float*)alloc((size_t)(G * 64 + G) * 4);
    float* cnt   = pool + (size_t)G * 64;
    float* asrc1 = (float*)alloc((size_t)N * 4 * 4);
    float* adst1 = (float*)alloc((size_t)N * 4 * 4);
    float* asrc2 = asrc1;             // alias: dead after gat1
    float* adst2 = adst1;
    u16* agg1    = (u16*)alloc((size_t)N * 128 * 2);
    u16* h1      = (u16*)alloc((size_t)N * 128 * 2);
    u16* h2      = h1;                // alias: h1 dead after gat1
    u16* agg2    = h1 + (size_t)N * 64;
    // al: gat spill buffer (deg>64 only). staged aliases al (temporally disjoint).
    float* al    = (float*)alloc((size_t)E * 16);
    int4* staged = (int4*)al;
    size_t full_need = (size_t)(p - (char*)d_ws);
    const bool cached = (ws_size >= full_need);
    const bool binned = cached && (B <= MAXB);

    // zeroing folded into k_detect (bcnt), k_consts (pool), k_coef1 (rpos)
    k_detect<<<1, 64, 0, stream>>>((const u32*)x, flag, bcnt, B);
    k_consts<<<1, 256, 0, stream>>>(We1, ae1, We2, ae2, as1, ad1, as2, ad2, flag, consts,
                                    pool, G * 64 + G);
    k_gemm5<128><<<512, 256, 0, stream>>>(x, W1, flag, -1, h1, N);
    k_coef1<<<(N * 2 + 255) / 256, 256, 0, stream>>>((const u32*)h1, consts, asrc1, adst1,
                                                     rpos, N);

    int NB = (N + 255) / 256;
    k_bhist<<<512, 256, 0, stream>>>(dst, rpos, bcnt, E, N, B);
    k_scan1<<<NB, 256, 0, stream>>>(rpos, roff + 1, bsum, N,
                                    bcnt, bbase, bfront, B, binned ? 1 : 0);
    k_scan3b<<<(N + 256) / 256, 256, 0, stream>>>(roff, bsum, rpos, N, NB);
    if (binned) {
        k_binA<<<(E + 2047) / 2048, 256, 0, stream>>>(dst, src, eattr, flag, bfront,
                                                      staged, E, N, B);
        k_binB<<<B, 256, 0, stream>>>(staged, bbase, roff, edata, N, E, B);
    } else {
        k_scatter<<<(E + 255) / 256, 256, 0, stream>>>(dst, src, eattr, flag, rpos,
                                                       edata, E, N);
    }

    int gatBlocks = (N * 64 + 255) / 256;
    if (cached) {
        k_gat1c<<<gatBlocks, 256, 0, stream>>>((const u32*)h1, asrc1, adst1, edata, roff,
                                               flag, consts, b1, al, (u32*)agg1, N, E);
    } else {
        k_gat1f<<<gatBlocks, 256, 0, stream>>>((const u32*)h1, asrc1, adst1, edata, roff,
                                               flag, consts, b1, (u32*)agg1, N, E);
    }
    k_gemm5<64><<<512, 256, 0, stream>>>(agg1, W2, flag, 0, h2, N);
    k_coef2<<<(N + 255) / 256, 256, 0, stream>>>((const u32*)h2, consts, asrc2, adst2, N);
    if (cached) {
        k_gat2c<<<gatBlocks, 256, 0, stream>>>(h2, asrc2, adst2, edata, roff, flag,
                                               consts, b2, al, agg2, N, E);
    } else {
        k_gat2f<<<gatBlocks, 256, 0, stream>>>(h2, asrc2, adst2, edata, roff, flag,
                                               consts, b2, agg2, N, E);
    }
    k_pool<<<(((N + 7) / 8) * 64 + 255) / 256, 256, 0, stream>>>(agg2, batch, pool, cnt, N, G);
    k_head<<<1, 64, 0, stream>>>(pool, cnt, Wp, bp, flag, d_out, G);
}